// Round 1
// 676.671 us; speedup vs baseline: 1.3617x; 1.3617x over previous
//
#include <hip/hip_runtime.h>
#include <cstddef>

#define BN_RS 0.99999500003749971f  // 1/sqrt(1+1e-5)

typedef __attribute__((ext_vector_type(8))) short bf16x8;
typedef __attribute__((ext_vector_type(4))) short bf16x4;
typedef __attribute__((ext_vector_type(4))) float f32x4;

#define LGKM0() asm volatile("s_waitcnt lgkmcnt(0)" ::: "memory")

__device__ __forceinline__ short f2bf(float f) {
    union { float f; unsigned u; } c; c.f = f;
    unsigned r = (c.u + 0x7fffu + ((c.u >> 16) & 1u)) >> 16;
    return (short)r;
}
__device__ __forceinline__ float bf2f(unsigned short h) {
    union { unsigned u; float f; } c; c.u = ((unsigned)h) << 16;
    return c.f;
}
__device__ __forceinline__ bf16x8 load8_bf(const float* __restrict__ p) {
    float4 a = *(const float4*)p;
    float4 b = *(const float4*)(p + 4);
    bf16x8 r;
    r[0] = f2bf(a.x); r[1] = f2bf(a.y); r[2] = f2bf(a.z); r[3] = f2bf(a.w);
    r[4] = f2bf(b.x); r[5] = f2bf(b.y); r[6] = f2bf(b.z); r[7] = f2bf(b.w);
    return r;
}

// ---------------- BN -> bf16 (node feats) ----------------
__global__ void bn_x_kernel(const float* __restrict__ in, const float* __restrict__ gamma,
                            const float* __restrict__ beta, unsigned short* __restrict__ xbf, int n4) {
    int i = blockIdx.x * blockDim.x + threadIdx.x;
    if (i >= n4) return;
    float4 v = ((const float4*)in)[i];
    float4 g = ((const float4*)gamma)[i & 7];
    float4 b = ((const float4*)beta)[i & 7];
    bf16x4 o;
    o[0] = f2bf(fmaf(v.x, g.x * BN_RS, b.x));
    o[1] = f2bf(fmaf(v.y, g.y * BN_RS, b.y));
    o[2] = f2bf(fmaf(v.z, g.z * BN_RS, b.z));
    o[3] = f2bf(fmaf(v.w, g.w * BN_RS, b.w));
    *(bf16x4*)(xbf + (size_t)i * 4) = o;
}

// ---------------- BN -> fp32 + bf16 (globals) ----------------
__global__ void bn_u_kernel(const float* __restrict__ in, const float* __restrict__ gamma,
                            const float* __restrict__ beta, float* __restrict__ ubuf,
                            unsigned short* __restrict__ ubf, int n4) {
    int i = blockIdx.x * blockDim.x + threadIdx.x;
    if (i >= n4) return;
    float4 v = ((const float4*)in)[i];
    float4 g = ((const float4*)gamma)[i & 7];
    float4 b = ((const float4*)beta)[i & 7];
    v.x = fmaf(v.x, g.x * BN_RS, b.x);
    v.y = fmaf(v.y, g.y * BN_RS, b.y);
    v.z = fmaf(v.z, g.z * BN_RS, b.z);
    v.w = fmaf(v.w, g.w * BN_RS, b.w);
    ((float4*)ubuf)[i] = v;
    bf16x4 o;
    o[0] = f2bf(v.x); o[1] = f2bf(v.y); o[2] = f2bf(v.z); o[3] = f2bf(v.w);
    *(bf16x4*)(ubf + (size_t)i * 4) = o;
}

// ---------------- CSR build ----------------
__global__ void hist_kernel(const int* __restrict__ idx, int* __restrict__ cnt, int n) {
    int i = blockIdx.x * blockDim.x + threadIdx.x;
    if (i < n) atomicAdd(&cnt[idx[i]], 1);
}

__global__ void scan_kernel(const int* __restrict__ cnt, int* __restrict__ row, int N) {
    __shared__ int sd[1024];
    int tid = threadIdx.x;
    int chunk = (N + 1023) >> 10;
    int lo = tid * chunk, hi = min(lo + chunk, N);
    int s = 0;
    for (int i = lo; i < hi; ++i) s += cnt[i];
    sd[tid] = s;
    __syncthreads();
    for (int off = 1; off < 1024; off <<= 1) {
        int t = (tid >= off) ? sd[tid - off] : 0;
        __syncthreads();
        sd[tid] += t;
        __syncthreads();
    }
    int run = sd[tid] - s;  // exclusive prefix
    for (int i = lo; i < hi; ++i) { row[i] = run; run += cnt[i]; }
    if (tid == 1023) row[N] = sd[1023];
}

__global__ void batch_src_kernel(const int* __restrict__ src, const int* __restrict__ batch,
                                 int* __restrict__ be, int E) {
    int e = blockIdx.x * blockDim.x + threadIdx.x;
    if (e < E) be[e] = batch[src[e]];
}

// scatter edges into dst-sorted perm order, packing {src, dst, bsrc, orig_e}
__global__ void scatter2_kernel(const int* __restrict__ src, const int* __restrict__ dst,
                                const int* __restrict__ bsrc, int* __restrict__ cursor,
                                int4* __restrict__ ip, int E) {
    int e = blockIdx.x * blockDim.x + threadIdx.x;
    if (e < E) {
        int d = dst[e];
        int slot = atomicAdd(&cursor[d], 1);
        ip[slot] = make_int4(src[e], d, bsrc[e], e);
    }
}

// ---------------- weight prep: edge W1/W2 -> bf16 MFMA fragment layout ----------------
// w1p: [l][s:4][t:4][lane:64][j:8], elem = W1_l[(32s+8q+j)*64 + 16t+n], lane=16q+n
// l==0, s==2 rows scaled by edge_gamma*BN_RS (BN fold); b1p l==0 gets beta fold.
__global__ void prep_kernel(const float* __restrict__ eW1, const float* __restrict__ eW2,
                            const float* __restrict__ eb1,
                            const float* __restrict__ egam, const float* __restrict__ ebet,
                            unsigned short* __restrict__ w1p, unsigned short* __restrict__ w2p,
                            float* __restrict__ b1p) {
    int gid = blockIdx.x * 256 + threadIdx.x;
    if (gid < 24576) {
        int l = gid / 8192, r = gid % 8192;
        int s = r / 2048, r2 = r % 2048;
        int t = r2 / 512, r3 = r2 % 512;
        int lane = r3 / 8, j = r3 % 8;
        int q = lane >> 4, n = lane & 15;
        float w = eW1[(size_t)l * 8192 + (32 * s + 8 * q + j) * 64 + 16 * t + n];
        if (l == 0 && s == 2) w *= egam[8 * q + j] * BN_RS;
        w1p[gid] = (unsigned short)f2bf(w);
    } else if (gid < 24576 + 6144) {
        int g = gid - 24576;
        int l = g / 2048, r = g % 2048;
        int s = r / 1024, r2 = r % 1024;
        int t = r2 / 512, r3 = r2 % 512;
        int lane = r3 / 8, j = r3 % 8;
        int q = lane >> 4, n = lane & 15;
        w2p[g] = (unsigned short)f2bf(eW2[(size_t)l * 2048 + (32 * s + 8 * q + j) * 32 + 16 * t + n]);
    } else if (gid < 24576 + 6144 + 192) {
        int g = gid - 24576 - 6144;
        int l = g / 64, c = g % 64;
        float bb = eb1[l * 64 + c];
        if (l == 0) {
            for (int k = 0; k < 32; ++k) bb = fmaf(ebet[k], eW1[(64 + k) * 64 + c], bb);
        }
        b1p[g] = bb;
    }
}

// ---------------- edge model (MFMA), perm order ----------------
// in0: gather raw fp32 edge_feats via orig id (BN folded in w1p/b1p). else: seq bf16 ein.
// Always writes bf16 eout (perm order); out2 additionally scatters fp32 to eoutf (orig order).
__global__ __launch_bounds__(256, 4) void edge_mfma2(
    const unsigned short* __restrict__ xbf,
    const float* __restrict__ ef_raw,
    const unsigned short* __restrict__ ein,
    unsigned short* __restrict__ eout,
    float* __restrict__ eoutf,
    const unsigned short* __restrict__ ubf,
    const int4* __restrict__ ip,
    const unsigned short* __restrict__ w1p, const unsigned short* __restrict__ w2p,
    const float* __restrict__ b1p, const float* __restrict__ b2,
    int in0, int out2, int E) {
    __shared__ unsigned short w1lds[8192];   // 16KB: [s][t][lane][8]
    __shared__ unsigned short hbuf[4][16 * 72];
    const int tid = threadIdx.x;
    const int wv = tid >> 6, lane = tid & 63;
    const int n = lane & 15, q = lane >> 4;

    // W1 fragments -> LDS (shared by all waves; frees 64 VGPRs vs register-resident)
#pragma unroll
    for (int c = 0; c < 4; ++c)
        *(bf16x8*)(w1lds + c * 2048 + tid * 8) = *(const bf16x8*)(w1p + c * 2048 + tid * 8);

    bf16x8 w2f[2][2];
#pragma unroll
    for (int s = 0; s < 2; ++s)
#pragma unroll
        for (int t = 0; t < 2; ++t)
            w2f[s][t] = *(const bf16x8*)(w2p + ((s * 2 + t) * 64 + lane) * 8);
    float b1v[4];
#pragma unroll
    for (int t = 0; t < 4; ++t) b1v[t] = b1p[16 * t + n];
    float b2v[2];
#pragma unroll
    for (int t = 0; t < 2; ++t) b2v[t] = b2[16 * t + n];

    const int wbase = blockIdx.x * 256 + wv * 64;
    // preload ALL tile indices up front: no in-loop index->gather dependent waits
    int4 ipt[4];
#pragma unroll
    for (int t = 0; t < 4; ++t) ipt[t] = ip[min(wbase + t * 16 + n, E - 1)];

    __syncthreads();  // w1lds ready

    bf16x8 g[2][4];
    auto load_tile = [&](int t4, bf16x8* af) {
        int4 p = ipt[t4];
        af[0] = *(const bf16x8*)(xbf + (size_t)p.x * 32 + 8 * q);
        af[1] = *(const bf16x8*)(xbf + (size_t)p.y * 32 + 8 * q);  // dst sorted -> L1 broadcast
        if (in0)
            af[2] = load8_bf(ef_raw + (size_t)p.w * 32 + 8 * q);
        else
            af[2] = *(const bf16x8*)(ein + (size_t)min(wbase + t4 * 16 + n, E - 1) * 32 + 8 * q);
        af[3] = *(const bf16x8*)(ubf + (size_t)p.z * 32 + 8 * q);
    };
    load_tile(0, g[0]);
    load_tile(1, g[1]);

    unsigned short* hw = hbuf[wv];
#pragma unroll
    for (int t4 = 0; t4 < 4; ++t4) {
        bf16x8* af = g[t4 & 1];

        f32x4 acc[4];
#pragma unroll
        for (int t = 0; t < 4; ++t) acc[t] = (f32x4){b1v[t], b1v[t], b1v[t], b1v[t]};
#pragma unroll
        for (int s = 0; s < 4; ++s)
#pragma unroll
            for (int t = 0; t < 4; ++t) {
                bf16x8 wf = *(const bf16x8*)(w1lds + (s * 4 + t) * 512 + lane * 8);
                acc[t] = __builtin_amdgcn_mfma_f32_16x16x32_bf16(af[s], wf, acc[t], 0, 0, 0);
            }

        if (t4 < 2) load_tile(t4 + 2, g[t4 & 1]);  // issue next gathers 2 tiles ahead

        LGKM0();  // prior hbuf reads + frag reads drained before overwrite
#pragma unroll
        for (int t = 0; t < 4; ++t)
#pragma unroll
            for (int r = 0; r < 4; ++r)
                hw[(4 * q + r) * 72 + 16 * t + n] = (unsigned short)f2bf(fmaxf(acc[t][r], 0.0f));
        LGKM0();  // writes visible to all lanes of this wave

        bf16x8 a2[2];
#pragma unroll
        for (int s = 0; s < 2; ++s)
            a2[s] = *(const bf16x8*)(hw + n * 72 + 32 * s + 8 * q);

        f32x4 acc2[2];
#pragma unroll
        for (int t = 0; t < 2; ++t) acc2[t] = (f32x4){b2v[t], b2v[t], b2v[t], b2v[t]};
#pragma unroll
        for (int s = 0; s < 2; ++s)
#pragma unroll
            for (int t = 0; t < 2; ++t)
                acc2[t] = __builtin_amdgcn_mfma_f32_16x16x32_bf16(a2[s], w2f[s][t], acc2[t], 0, 0, 0);

        const int rowbase = wbase + t4 * 16 + 4 * q;
#pragma unroll
        for (int t = 0; t < 2; ++t)
#pragma unroll
            for (int r = 0; r < 4; ++r) {
                int er = rowbase + r;
                if (er < E) eout[(size_t)er * 32 + 16 * t + n] = (unsigned short)f2bf(acc2[t][r]);
            }
        if (out2) {
            int ww[4];
#pragma unroll
            for (int r = 0; r < 4; ++r) ww[r] = __shfl(ipt[t4].w, 4 * q + r);
#pragma unroll
            for (int t = 0; t < 2; ++t)
#pragma unroll
                for (int r = 0; r < 4; ++r) {
                    int er = rowbase + r;
                    if (er < E) eoutf[(size_t)ww[r] * 32 + 16 * t + n] = acc2[t][r];
                }
        }
    }
}

// ---------------- agg = scatter_mean(e' -> dst): pure streaming over perm order, fp32 out ----------------
__global__ void agg2_kernel(const int* __restrict__ row, const unsigned short* __restrict__ ebf,
                            float* __restrict__ aggf, int N) {
    int t = blockIdx.x * blockDim.x + threadIdx.x;
    int node = t >> 3;
    if (node >= N) return;
    int c = (t & 7) * 4;
    int s = row[node], e = row[node + 1];
    float a0 = 0.f, a1 = 0.f, a2 = 0.f, a3 = 0.f;
    for (int j = s; j < e; ++j) {
        ushort4 v = *(const ushort4*)(ebf + (size_t)j * 32 + c);
        a0 += bf2f(v.x); a1 += bf2f(v.y); a2 += bf2f(v.z); a3 += bf2f(v.w);
    }
    float inv = 1.0f / fmaxf((float)(e - s), 1.0f);
    float4 o = {a0 * inv, a1 * inv, a2 * inv, a3 * inv};
    *(float4*)(aggf + (size_t)node * 32 + c) = o;
}

// ---------------- node model (MFMA): x' = MLP([x, agg, u[batch]]) ----------------
__global__ __launch_bounds__(256) void node_mfma2(
    unsigned short* __restrict__ xbf, const float* __restrict__ aggf,
    const unsigned short* __restrict__ ubf, const int* __restrict__ batch,
    const float* __restrict__ W1, const float* __restrict__ b1,
    const float* __restrict__ W2, const float* __restrict__ b2,
    float* __restrict__ xf_out, int write_f32, int N) {
    __shared__ unsigned short hbuf[4][16 * 72];
    const int tid = threadIdx.x;
    const int wv = tid >> 6, lane = tid & 63;
    const int n = lane & 15, q = lane >> 4;

    bf16x8 w1f[3][4];
#pragma unroll
    for (int s = 0; s < 3; ++s)
#pragma unroll
        for (int t = 0; t < 4; ++t)
#pragma unroll
            for (int j = 0; j < 8; ++j)
                w1f[s][t][j] = f2bf(W1[(32 * s + 8 * q + j) * 64 + 16 * t + n]);
    bf16x8 w2f[2][2];
#pragma unroll
    for (int s = 0; s < 2; ++s)
#pragma unroll
        for (int t = 0; t < 2; ++t)
#pragma unroll
            for (int j = 0; j < 8; ++j)
                w2f[s][t][j] = f2bf(W2[(32 * s + 8 * q + j) * 32 + 16 * t + n]);
    float b1v[4];
#pragma unroll
    for (int t = 0; t < 4; ++t) b1v[t] = b1[16 * t + n];
    float b2v[2];
#pragma unroll
    for (int t = 0; t < 2; ++t) b2v[t] = b2[16 * t + n];

    const int base_n = blockIdx.x * 256 + wv * 64;

    auto load_tile = [&](int t4, bf16x8* af) {
        int nidx = min(base_n + t4 * 16 + n, N - 1);
        int bi = batch[nidx];
        af[0] = *(const bf16x8*)(xbf + (size_t)nidx * 32 + 8 * q);
        float4 a0 = *(const float4*)(aggf + (size_t)nidx * 32 + 8 * q);
        float4 a1 = *(const float4*)(aggf + (size_t)nidx * 32 + 8 * q + 4);
        bf16x8 agv;
        agv[0] = f2bf(a0.x); agv[1] = f2bf(a0.y); agv[2] = f2bf(a0.z); agv[3] = f2bf(a0.w);
        agv[4] = f2bf(a1.x); agv[5] = f2bf(a1.y); agv[6] = f2bf(a1.z); agv[7] = f2bf(a1.w);
        af[1] = agv;
        af[2] = *(const bf16x8*)(ubf + (size_t)bi * 32 + 8 * q);
    };

    unsigned short* hw = hbuf[wv];
    bf16x8 afb[2][3];
    load_tile(0, afb[0]);

#pragma unroll
    for (int t4 = 0; t4 < 4; ++t4) {
        bf16x8* af = afb[t4 & 1];
        if (t4 < 3) load_tile(t4 + 1, afb[(t4 + 1) & 1]);

        f32x4 acc[4];
#pragma unroll
        for (int t = 0; t < 4; ++t) acc[t] = (f32x4){b1v[t], b1v[t], b1v[t], b1v[t]};
#pragma unroll
        for (int s = 0; s < 3; ++s)
#pragma unroll
            for (int t = 0; t < 4; ++t)
                acc[t] = __builtin_amdgcn_mfma_f32_16x16x32_bf16(af[s], w1f[s][t], acc[t], 0, 0, 0);

        LGKM0();
#pragma unroll
        for (int t = 0; t < 4; ++t)
#pragma unroll
            for (int r = 0; r < 4; ++r)
                hw[(4 * q + r) * 72 + 16 * t + n] = (unsigned short)f2bf(fmaxf(acc[t][r], 0.0f));
        LGKM0();

        bf16x8 a2[2];
#pragma unroll
        for (int s = 0; s < 2; ++s)
            a2[s] = *(const bf16x8*)(hw + n * 72 + 32 * s + 8 * q);

        f32x4 acc2[2];
#pragma unroll
        for (int t = 0; t < 2; ++t) acc2[t] = (f32x4){b2v[t], b2v[t], b2v[t], b2v[t]};
#pragma unroll
        for (int s = 0; s < 2; ++s)
#pragma unroll
            for (int t = 0; t < 2; ++t)
                acc2[t] = __builtin_amdgcn_mfma_f32_16x16x32_bf16(a2[s], w2f[s][t], acc2[t], 0, 0, 0);

        int nrow = base_n + t4 * 16 + 4 * q;
#pragma unroll
        for (int t = 0; t < 2; ++t)
#pragma unroll
            for (int r = 0; r < 4; ++r) {
                int nr = nrow + r;
                if (nr < N) {
                    xbf[(size_t)nr * 32 + 16 * t + n] = (unsigned short)f2bf(acc2[t][r]);
                    if (write_f32) xf_out[(size_t)nr * 32 + 16 * t + n] = acc2[t][r];
                }
            }
    }
}

// ---------------- xg partial sums (batch sorted): atomicAdd per segment-flush ----------------
__global__ void xg_kernel(const unsigned short* __restrict__ xbf, const int* __restrict__ batch,
                          int N, float* __restrict__ xg) {
    int nblk = gridDim.x;
    int chunk = (N + nblk - 1) / nblk;
    int start = blockIdx.x * chunk;
    int end = min(start + chunk, N);
    int c = threadIdx.x & 31;
    int g = threadIdx.x >> 5;  // 8 node-lanes
    float acc = 0.0f;
    int cur = -1;
    for (int i = start + g; i < end; i += 8) {
        int b = batch[i];
        float v = bf2f(xbf[(size_t)i * 32 + c]);
        if (b != cur) {
            if (cur >= 0) atomicAdd(&xg[cur * 32 + c], acc);
            cur = b; acc = v;
        } else {
            acc += v;
        }
    }
    if (cur >= 0) atomicAdd(&xg[cur * 32 + c], acc);
}

// ---------------- global model: u' = MLP([u, xg/cnt]) ----------------
__device__ __forceinline__ int lbound(const int* __restrict__ a, int nn, int v) {
    int lo = 0, hi = nn;
    while (lo < hi) {
        int mid = (lo + hi) >> 1;
        if (a[mid] < v) lo = mid + 1; else hi = mid;
    }
    return lo;
}

__global__ void glob_kernel(const float* __restrict__ u, const float* __restrict__ xg,
                            const int* __restrict__ batch, int N,
                            const float* __restrict__ W1, const float* __restrict__ b1,
                            const float* __restrict__ W2, const float* __restrict__ b2,
                            float* __restrict__ u_dst, unsigned short* __restrict__ ubf_dst) {
    int r = blockIdx.x;
    int t = threadIdx.x;  // 64 threads
    __shared__ float gin[64];
    __shared__ float hs[64];
    __shared__ int cnts;
    if (t == 0) cnts = lbound(batch, N, r + 1) - lbound(batch, N, r);
    __syncthreads();
    if (t < 32)
        gin[t] = u[r * 32 + t];
    else
        gin[t] = xg[r * 32 + (t - 32)] / fmaxf((float)cnts, 1.0f);
    __syncthreads();
    float h = b1[t];
#pragma unroll
    for (int k = 0; k < 64; ++k) h = fmaf(gin[k], W1[k * 64 + t], h);
    hs[t] = fmaxf(h, 0.0f);
    __syncthreads();
    if (t < 32) {
        float o = b2[t];
#pragma unroll
        for (int k = 0; k < 64; ++k) o = fmaf(hs[k], W2[k * 32 + t], o);
        u_dst[r * 32 + t] = o;
        ubf_dst[r * 32 + t] = (unsigned short)f2bf(o);
    }
}

extern "C" void kernel_launch(void* const* d_in, const int* in_sizes, int n_in,
                              void* d_out, int out_size, void* d_ws, size_t ws_size,
                              hipStream_t stream) {
    const float* node_feats = (const float*)d_in[0];
    const int* edge_index = (const int*)d_in[1];
    const float* edge_feats = (const float*)d_in[2];
    const float* glob_feats = (const float*)d_in[3];
    const int* batch = (const int*)d_in[4];
    const float* node_gamma = (const float*)d_in[5];
    const float* node_beta = (const float*)d_in[6];
    const float* edge_gamma = (const float*)d_in[7];
    const float* edge_beta = (const float*)d_in[8];
    const float* glob_gamma = (const float*)d_in[9];
    const float* glob_beta = (const float*)d_in[10];
    const float* edge_W1 = (const float*)d_in[11];
    const float* edge_b1 = (const float*)d_in[12];
    const float* edge_W2 = (const float*)d_in[13];
    const float* edge_b2 = (const float*)d_in[14];
    const float* node_W1 = (const float*)d_in[15];
    const float* node_b1 = (const float*)d_in[16];
    const float* node_W2 = (const float*)d_in[17];
    const float* node_b2 = (const float*)d_in[18];
    const float* glob_W1 = (const float*)d_in[19];
    const float* glob_b1 = (const float*)d_in[20];
    const float* glob_W2 = (const float*)d_in[21];
    const float* glob_b2 = (const float*)d_in[22];

    const int N = in_sizes[0] / 32;
    const int E = in_sizes[1] / 2;
    const int B = in_sizes[3] / 32;

    float* x_out = (float*)d_out;           // N x 32
    float* e_out = x_out + (size_t)N * 32;  // E x 32
    float* u_out = e_out + (size_t)E * 32;  // B x 32

    // workspace carve (all chunks multiples of 16B)
    char* ws = (char*)d_ws;
    unsigned short* x_bf = (unsigned short*)ws;  ws += (size_t)N * 32 * 2;
    float* aggf = (float*)ws;                    ws += (size_t)N * 32 * 4;
    unsigned short* u_bf = (unsigned short*)ws;  ws += 2048;
    float* u_buf = (float*)ws;                   ws += 4096;
    float* xg = (float*)ws;                      ws += 4096;
    int4* ip = (int4*)ws;                        ws += (size_t)E * 16;
    int* rowp = (int*)ws;                        ws += (size_t)(N + 4) * 4;
    int* cursor = (int*)ws;                      ws += (size_t)N * 4;
    int* hist = (int*)ws;                        ws += (size_t)N * 4;
    int* bsrc = (int*)ws;                        ws += (size_t)E * 4;
    unsigned short* w1p = (unsigned short*)ws;   ws += 24576 * 2;
    unsigned short* w2p = (unsigned short*)ws;   ws += 6144 * 2;
    float* b1p = (float*)ws;                     ws += 192 * 4;
    unsigned short* e_bf = (unsigned short*)ws;  ws += (size_t)E * 32 * 2;  // perm-order e'

    const int* ei_src = edge_index;
    const int* ei_dst = edge_index + E;

    bn_x_kernel<<<(N * 8 + 255) / 256, 256, 0, stream>>>(node_feats, node_gamma, node_beta, x_bf, N * 8);
    bn_u_kernel<<<(B * 8 + 255) / 256, 256, 0, stream>>>(glob_feats, glob_gamma, glob_beta, u_buf, u_bf, B * 8);
    prep_kernel<<<121, 256, 0, stream>>>(edge_W1, edge_W2, edge_b1, edge_gamma, edge_beta, w1p, w2p, b1p);

    hipMemsetAsync(hist, 0, (size_t)N * 4, stream);
    hist_kernel<<<(E + 255) / 256, 256, 0, stream>>>(ei_dst, hist, E);
    scan_kernel<<<1, 1024, 0, stream>>>(hist, rowp, N);
    hipMemcpyAsync(cursor, rowp, (size_t)N * 4, hipMemcpyDeviceToDevice, stream);
    batch_src_kernel<<<(E + 255) / 256, 256, 0, stream>>>(ei_src, batch, bsrc, E);
    scatter2_kernel<<<(E + 255) / 256, 256, 0, stream>>>(ei_src, ei_dst, bsrc, cursor, ip, E);

    for (int l = 0; l < 3; ++l) {
        hipMemsetAsync(xg, 0, (size_t)B * 32 * 4, stream);

        edge_mfma2<<<(E + 255) / 256, 256, 0, stream>>>(
            x_bf, edge_feats, e_bf, e_bf, e_out, u_bf, ip,
            w1p + (size_t)l * 8192, w2p + (size_t)l * 2048,
            b1p + l * 64, edge_b2 + l * 32,
            (l == 0) ? 1 : 0, (l == 2) ? 1 : 0, E);
        agg2_kernel<<<(N * 8 + 255) / 256, 256, 0, stream>>>(rowp, e_bf, aggf, N);
        node_mfma2<<<(N + 255) / 256, 256, 0, stream>>>(
            x_bf, aggf, u_bf, batch,
            node_W1 + (size_t)l * 96 * 64, node_b1 + l * 64,
            node_W2 + (size_t)l * 64 * 32, node_b2 + l * 32,
            x_out, (l == 2) ? 1 : 0, N);
        xg_kernel<<<256, 256, 0, stream>>>(x_bf, batch, N, xg);
        glob_kernel<<<B, 64, 0, stream>>>(
            u_buf, xg, batch, N,
            glob_W1 + (size_t)l * 64 * 64, glob_b1 + l * 64,
            glob_W2 + (size_t)l * 64 * 32, glob_b2 + l * 32,
            (l == 2) ? u_out : u_buf, u_bf);
    }
}